// Round 1
// baseline (398.453 us; speedup 1.0000x reference)
//
#include <hip/hip_runtime.h>

#define NF 27
#define FD 128
#define EMB (NF * FD)        // 3456
#define NPAIR 351            // 27*26/2
#define OUTS (EMB + NPAIR)   // 3807
#define BLK 256

// One block per batch row.
// Phase 1: coalesced float4 loads -> LDS (swizzled) + direct copy-out.
// Phase 2: 28 lanes compute 4x4 tiles of the 27x27 Gram upper triangle.
//
// LDS layout: logical (f, dd) float4 chunk stored at ldsT[(dd + (f>>2)) & 31][f],
// row stride 29 float4 (odd). Bank-group of a read = (5*dd + I + r) mod 8,
// so the 7 distinct I (or J) values across lanes hit distinct bank groups.
__global__ __launch_bounds__(BLK) void fi_kernel(const float* __restrict__ emb,
                                                 float* __restrict__ out) {
    __shared__ float4 ldsT[32][29];
    const int b = blockIdx.x;
    const int t = threadIdx.x;
    const float* ebase = emb + (size_t)b * EMB;
    float* obase = out + (size_t)b * OUTS;
    const float4* e4 = reinterpret_cast<const float4*>(ebase);

    // zero pad row f=27 (read by tile (6,6) but never stored)
    if (t < 32) ldsT[t][27] = make_float4(0.f, 0.f, 0.f, 0.f);

    // ---- Phase 1: load 864 float4 (27 rows x 32 chunks), stage + copy-out ----
    #pragma unroll
    for (int it = 0; it < 4; ++it) {
        int g = t + it * BLK;
        if (g < 864) {
            float4 v = e4[g];
            int f = g >> 5;       // feature row 0..26
            int dd = g & 31;      // float4 chunk within row
            ldsT[(dd + (f >> 2)) & 31][f] = v;
            float* o = obase + (g << 2);
            o[0] = v.x; o[1] = v.y; o[2] = v.z; o[3] = v.w;
        }
    }
    __syncthreads();

    // ---- Phase 2: 28 upper-triangular 4x4 tiles (I<=J over 7x7 tile grid) ----
    if (t < 28) {
        int T = t, I = 0;
        while (T >= 7 - I) { T -= 7 - I; ++I; }
        const int J = I + T;

        float acc[4][4] = {};
        #pragma unroll 4
        for (int dd = 0; dd < 32; ++dd) {
            const int sA = (dd + I) & 31;
            const int sB = (dd + J) & 31;
            float4 A[4], Bv[4];
            #pragma unroll
            for (int r = 0; r < 4; ++r) A[r] = ldsT[sA][4 * I + r];
            #pragma unroll
            for (int s = 0; s < 4; ++s) Bv[s] = ldsT[sB][4 * J + s];
            #pragma unroll
            for (int r = 0; r < 4; ++r)
                #pragma unroll
                for (int s = 0; s < 4; ++s)
                    acc[r][s] += A[r].x * Bv[s].x + A[r].y * Bv[s].y +
                                 A[r].z * Bv[s].z + A[r].w * Bv[s].w;
        }

        #pragma unroll
        for (int r = 0; r < 4; ++r) {
            const int i = 4 * I + r;
            #pragma unroll
            for (int s = 0; s < 4; ++s) {
                const int j = 4 * J + s;
                if (j < NF && i < j) {
                    // triu_indices(27, k=1) row-major index
                    const int idx = i * 26 - (i * (i - 1)) / 2 + (j - i - 1);
                    obase[EMB + idx] = acc[r][s];
                }
            }
        }
    }
}

extern "C" void kernel_launch(void* const* d_in, const int* in_sizes, int n_in,
                              void* d_out, int out_size, void* d_ws, size_t ws_size,
                              hipStream_t stream) {
    const float* emb = (const float*)d_in[0];
    float* out = (float*)d_out;
    const int B = in_sizes[0] / EMB;   // 16384
    fi_kernel<<<B, BLK, 0, stream>>>(emb, out);
}

// Round 2
// 391.206 us; speedup vs baseline: 1.0185x; 1.0185x over previous
//
#include <hip/hip_runtime.h>

#define NF 27
#define FD 128
#define EMB (NF * FD)        // 3456
#define NPAIR 351            // 27*26/2
#define OUTS (EMB + NPAIR)   // 3807
#define BLK 256

// One block per batch row.
// Phase 1: coalesced float4 loads -> LDS (swizzled) + direct copy-out.
// Phase 2: ALL 4 waves compute: thread = (tile 0..27) x (dgroup 0..7).
//   Each thread does 4 of the 32 d-chunks (dd = dg + 8k), then the 8
//   d-partials reduce in-register via __shfl_xor over the low 3 lane bits.
//
// LDS layout: chunk (f, dd) lives at ldsT[(dd + (f>>2)) & 31][f], row
// stride 29 float4 (odd). Read bank-group = (5*dg + I + r) mod 8: the
// 5*dg term sweeps all 8 groups -> conflict-free b128 reads; same-(dg)
// lanes across tiles with equal I read the SAME address (broadcast).
__global__ __launch_bounds__(BLK) void fi_kernel(const float* __restrict__ emb,
                                                 float* __restrict__ out) {
    __shared__ float4 ldsT[32][29];
    const int b = blockIdx.x;
    const int t = threadIdx.x;
    const float* ebase = emb + (size_t)b * EMB;
    float* obase = out + (size_t)b * OUTS;
    const float4* e4 = reinterpret_cast<const float4*>(ebase);

    // zero pad row f=27 in every slot (read by tile (6,6), never stored)
    if (t < 32) ldsT[t][27] = make_float4(0.f, 0.f, 0.f, 0.f);

    // ---- Phase 1: load 864 float4 (27 rows x 32 chunks), stage + copy-out ----
    #pragma unroll
    for (int it = 0; it < 4; ++it) {
        int g = t + it * BLK;
        if (g < 864) {
            float4 v = e4[g];
            int f = g >> 5;       // feature row 0..26
            int dd = g & 31;      // float4 chunk within row
            ldsT[(dd + (f >> 2)) & 31][f] = v;
            float* o = obase + (g << 2);
            o[0] = v.x; o[1] = v.y; o[2] = v.z; o[3] = v.w;
        }
    }
    __syncthreads();

    // ---- Phase 2: 28 tiles x 8 d-groups = 224 threads ----
    if (t < 224) {
        const int tile = t >> 3;
        const int dg = t & 7;
        int T = tile, I = 0;
        while (T >= 7 - I) { T -= 7 - I; ++I; }
        const int J = I + T;

        float acc[4][4] = {};
        #pragma unroll
        for (int k = 0; k < 4; ++k) {
            const int dd = dg + 8 * k;
            const int sA = (dd + I) & 31;
            const int sB = (dd + J) & 31;
            float4 A[4], Bv[4];
            #pragma unroll
            for (int r = 0; r < 4; ++r) A[r] = ldsT[sA][4 * I + r];
            #pragma unroll
            for (int s = 0; s < 4; ++s) Bv[s] = ldsT[sB][4 * J + s];
            #pragma unroll
            for (int r = 0; r < 4; ++r)
                #pragma unroll
                for (int s = 0; s < 4; ++s)
                    acc[r][s] += A[r].x * Bv[s].x + A[r].y * Bv[s].y +
                                 A[r].z * Bv[s].z + A[r].w * Bv[s].w;
        }

        // reduce the 8 d-group partials (lanes differing in bits 0..2)
        #pragma unroll
        for (int r = 0; r < 4; ++r) {
            #pragma unroll
            for (int s = 0; s < 4; ++s) {
                float v = acc[r][s];
                v += __shfl_xor(v, 1);
                v += __shfl_xor(v, 2);
                v += __shfl_xor(v, 4);
                acc[r][s] = v;
            }
        }

        if (dg == 0) {
            #pragma unroll
            for (int r = 0; r < 4; ++r) {
                const int i = 4 * I + r;
                #pragma unroll
                for (int s = 0; s < 4; ++s) {
                    const int j = 4 * J + s;
                    if (j < NF && i < j) {
                        const int idx = i * 26 - (i * (i - 1)) / 2 + (j - i - 1);
                        obase[EMB + idx] = acc[r][s];
                    }
                }
            }
        }
    }
}

extern "C" void kernel_launch(void* const* d_in, const int* in_sizes, int n_in,
                              void* d_out, int out_size, void* d_ws, size_t ws_size,
                              hipStream_t stream) {
    const float* emb = (const float*)d_in[0];
    float* out = (float*)d_out;
    const int B = in_sizes[0] / EMB;   // 16384
    fi_kernel<<<B, BLK, 0, stream>>>(emb, out);
}